// Round 4
// baseline (359.845 us; speedup 1.0000x reference)
//
#include <hip/hip_runtime.h>
#include <math.h>

#define Y_ 1024
#define X_ 2048
#define YX_ (Y_*X_)
#define RAD_ 12
#define NT_ 25
#define ND_ 27
#define APC_ 15
#define PAD_ 16

struct W25 { float w[NT_]; };
struct D27 { float d[ND_]; };

// ---------------------------------------------------------------------------
// K1: Y-smooth (circular) of the 7 input channels, 16 output rows per thread.
//   z in [0,4]  -> y channels (m00,m01,m10,m11,s)
//   z in [5,6]  -> symmetrized v channels computed on the fly:
//       v_sym0(y,x) = 0.5*(v0(y,x) - v0(Y-1-y,x))
//       v_sym1(y,x) = 0.5*(v1(y,x) + v1(Y-1-y,x))
// ---------------------------------------------------------------------------
__global__ __launch_bounds__(256) void ksmooth_y7(
    const float* __restrict__ yin, const float* __restrict__ vin,
    float* __restrict__ out, W25 W)
{
  const int z  = blockIdx.z;                       // 0..6 (block-uniform)
  const int y0 = blockIdx.y * 16;                  // 16 output rows
  const int xo = (blockIdx.x * 256 + threadIdx.x) * 4;

  float4 acc[16];
#pragma unroll
  for (int j = 0; j < 16; ++j) acc[j] = make_float4(0.f, 0.f, 0.f, 0.f);

#pragma unroll
  for (int t = 0; t < 40; ++t) {
    const int r = (y0 - RAD_ + t + Y_) & (Y_ - 1);
    float4 val;
    if (z < 5) {
      val = *(const float4*)(yin + z * YX_ + r * X_ + xo);
    } else {
      const int   c   = z - 5;
      const float sgn = (c == 0) ? -1.f : 1.f;
      float4 a = *(const float4*)(vin + c * YX_ + r * X_ + xo);
      float4 b = *(const float4*)(vin + c * YX_ + (Y_ - 1 - r) * X_ + xo);
      val.x = 0.5f * (a.x + sgn * b.x);
      val.y = 0.5f * (a.y + sgn * b.y);
      val.z = 0.5f * (a.z + sgn * b.z);
      val.w = 0.5f * (a.w + sgn * b.w);
    }
#pragma unroll
    for (int j = 0; j < 16; ++j) {
      const int k = t - j;                         // compile-time tap index
      if (k >= 0 && k < NT_) {
        const float wk = W.w[k];
        acc[j].x += wk * val.x; acc[j].y += wk * val.y;
        acc[j].z += wk * val.z; acc[j].w += wk * val.w;
      }
    }
  }
#pragma unroll
  for (int j = 0; j < 16; ++j)
    *(float4*)(out + z * YX_ + (y0 + j) * X_ + xo) = acc[j];
}

// ---------------------------------------------------------------------------
// K2: fused X-smooth + gradient + pointwise algebra + AP-cut.
// Inputs: gY = Y-smoothed 7ch. Derivatives of fully-smoothed fields:
//   dXg = 27-tap conv with D (derivative-of-kernel), row y only
//   dYg = 25-tap X-smooth of 0.5*(gY[y+1]-gY[y-1])   (circular y)
// Groups fully inside the AP cut (x0<12 or x0>2032) just write zeros.
// The remaining groups take one uniform fast path; 4-float over-reads at the
// array ends land in the pad before gY / the B buffer after gY.
// ---------------------------------------------------------------------------
__global__ __launch_bounds__(256) void kgradpoint(
    const float* __restrict__ gY,    // 7ch y-smoothed
    const float* __restrict__ yin,   // raw y, 5ch
    const float* __restrict__ vin,   // raw v, 2ch
    float* __restrict__ out,         // 5ch pre-postprocess
    W25 W, D27 D)
{
  const int yy = blockIdx.y;
  const int x0 = (blockIdx.x * 256 + threadIdx.x) * 4;

  if (x0 < RAD_ || x0 > X_ - PAD_) {   // x0 in {0,4,8} or {2036..2044}: all masked
#pragma unroll
    for (int zc = 0; zc < 5; ++zc)
      *(float4*)(out + zc * YX_ + yy * X_ + x0) = make_float4(0.f, 0.f, 0.f, 0.f);
    return;
  }

  const int yu = (yy + 1) & (Y_ - 1);
  const int yd = (yy - 1 + Y_) & (Y_ - 1);

  float dYg[7][4], dXg[7][4];
#pragma unroll
  for (int c = 0; c < 7; ++c) {
    const float* rc = gY + c * YX_ + yy * X_;
    const float* ru = gY + c * YX_ + yu * X_;
    const float* rd = gY + c * YX_ + yd * X_;

    float wb[36];                      // row y window: x0-16 .. x0+19
#pragma unroll
    for (int i = 0; i < 9; ++i) {
      float4 t = *(const float4*)(rc + x0 - 16 + 4 * i);
      wb[4*i+0] = t.x; wb[4*i+1] = t.y; wb[4*i+2] = t.z; wb[4*i+3] = t.w;
    }
#pragma unroll
    for (int j = 0; j < 4; ++j) {
      float s = 0.f;
#pragma unroll
      for (int t = 0; t < ND_; ++t) s += D.d[t] * wb[3 + j + t];
      dXg[c][j] = s;
    }

    float db[28];                      // 0.5*(row y+1 - row y-1): x0-12 .. x0+15
#pragma unroll
    for (int i = 0; i < 7; ++i) {
      float4 u = *(const float4*)(ru + x0 - 12 + 4 * i);
      float4 d = *(const float4*)(rd + x0 - 12 + 4 * i);
      db[4*i+0] = 0.5f * (u.x - d.x); db[4*i+1] = 0.5f * (u.y - d.y);
      db[4*i+2] = 0.5f * (u.z - d.z); db[4*i+3] = 0.5f * (u.w - d.w);
    }
#pragma unroll
    for (int j = 0; j < 4; ++j) {
      float s = 0.f;
#pragma unroll
      for (int t = 0; t < NT_; ++t) s += W.w[t] * db[j + t];
      dYg[c][j] = s;
    }
  }

  // raw fields
  float rm[5][4];
#pragma unroll
  for (int zc = 0; zc < 5; ++zc) {
    float4 t = *(const float4*)(yin + zc * YX_ + yy * X_ + x0);
    rm[zc][0] = t.x; rm[zc][1] = t.y; rm[zc][2] = t.z; rm[zc][3] = t.w;
  }
  float vs0[4], vs1[4];
  {
    float4 a = *(const float4*)(vin + 0 * YX_ + yy * X_ + x0);
    float4 b = *(const float4*)(vin + 0 * YX_ + (Y_ - 1 - yy) * X_ + x0);
    vs0[0] = 0.5f * (a.x - b.x); vs0[1] = 0.5f * (a.y - b.y);
    vs0[2] = 0.5f * (a.z - b.z); vs0[3] = 0.5f * (a.w - b.w);
    float4 c = *(const float4*)(vin + 1 * YX_ + yy * X_ + x0);
    float4 d = *(const float4*)(vin + 1 * YX_ + (Y_ - 1 - yy) * X_ + x0);
    vs1[0] = 0.5f * (c.x + d.x); vs1[1] = 0.5f * (c.y + d.y);
    vs1[2] = 0.5f * (c.z + d.z); vs1[3] = 0.5f * (c.w + d.w);
  }

  float o[5][4];
#pragma unroll
  for (int j = 0; j < 4; ++j) {
    const float m00r = rm[0][j], m01r = rm[1][j], m10r = rm[2][j], m11r = rm[3][j];
    const float sr   = rm[4][j];
    const float v0   = vs0[j], v1 = vs1[j];

    const float w_  = -0.5f * (dXg[5][j] - dYg[6][j]);   // vorticity O[0][1]
    const float trE = dYg[5][j] + dXg[6][j];
    const float trm = m00r + m11r;

    const float lhs00 = v0 * dYg[0][j] + v1 * dXg[0][j] + w_ * (m10r + m01r);
    const float lhs01 = v0 * dYg[1][j] + v1 * dXg[1][j] + w_ * (m11r - m00r);
    const float lhs10 = v0 * dYg[2][j] + v1 * dXg[2][j] + w_ * (m11r - m00r);
    const float lhs11 = v0 * dYg[3][j] + v1 * dXg[3][j] - w_ * (m01r + m10r);

    const float f  = -(0.11f - 0.099f * sr)
                   + (0.767f + 0.055f * sr) * trE
                   + (0.732f - 0.59f  * sr) * trm;
    const float cd = (0.069f - 0.048f * sr) * trm;
    const float sd = -(v0 * dYg[4][j] + v1 * dXg[4][j]);

    const int   xg   = x0 + j;
    const float mask = (xg < APC_ || xg >= X_ - APC_) ? 0.f : 1.f;
    o[0][j] = mask * (f * m00r + cd - lhs00);
    o[1][j] = mask * (f * m01r      - lhs01);
    o[2][j] = mask * (f * m10r      - lhs10);
    o[3][j] = mask * (f * m11r      - lhs11);
    o[4][j] = mask * sd;
  }
#pragma unroll
  for (int zc = 0; zc < 5; ++zc)
    *(float4*)(out + zc * YX_ + yy * X_ + x0) =
        make_float4(o[zc][0], o[zc][1], o[zc][2], o[zc][3]);
}

// ---------------------------------------------------------------------------
// K3: fused postprocess smooth (Y circular then X edge-replicate) in one pass.
// Per thread: X-smooth each of 40 input rows into 4 values, accumulate into
// 16 Y-accumulators. Edge-replicate == zero-pad here because the masked AP
// columns are exactly zero, so OOB taps contribute 0.
// ---------------------------------------------------------------------------
__global__ __launch_bounds__(256) void kpost(
    const float* __restrict__ B, float* __restrict__ out, W25 W)
{
  const int z  = blockIdx.z;
  const int y0 = blockIdx.y * 16;
  const int xo = (blockIdx.x * 256 + threadIdx.x) * 4;
  const bool fast = (xo >= RAD_ && xo <= X_ - PAD_);

  float4 acc[16];
#pragma unroll
  for (int j = 0; j < 16; ++j) acc[j] = make_float4(0.f, 0.f, 0.f, 0.f);

  for (int t = 0; t < 40; ++t) {
    const int r = (y0 - RAD_ + t + Y_) & (Y_ - 1);
    const float* row = B + z * YX_ + r * X_;
    float xb[28];
    if (fast) {
#pragma unroll
      for (int i = 0; i < 7; ++i) {
        float4 v = *(const float4*)(row + xo - 12 + 4 * i);
        xb[4*i+0] = v.x; xb[4*i+1] = v.y; xb[4*i+2] = v.z; xb[4*i+3] = v.w;
      }
    } else {
#pragma unroll
      for (int i = 0; i < 28; ++i) {
        const int xx = xo - 12 + i;
        xb[i] = (xx >= 0 && xx < X_) ? row[xx] : 0.f;
      }
    }
    float4 xs;
    {
      float a0 = 0.f, a1 = 0.f, a2 = 0.f, a3 = 0.f;
#pragma unroll
      for (int k = 0; k < NT_; ++k) {
        const float wk = W.w[k];
        a0 += wk * xb[k + 0]; a1 += wk * xb[k + 1];
        a2 += wk * xb[k + 2]; a3 += wk * xb[k + 3];
      }
      xs = make_float4(a0, a1, a2, a3);
    }
#pragma unroll
    for (int j = 0; j < 16; ++j) {
      const int k = t - j;
      if (k >= 0 && k < NT_) {
        const float wk = W.w[k];
        acc[j].x += wk * xs.x; acc[j].y += wk * xs.y;
        acc[j].z += wk * xs.z; acc[j].w += wk * xs.w;
      }
    }
  }
#pragma unroll
  for (int j = 0; j < 16; ++j)
    *(float4*)(out + z * YX_ + (y0 + j) * X_ + xo) = acc[j];
}

// ---------------------------------------------------------------------------
extern "C" void kernel_launch(void* const* d_in, const int* in_sizes, int n_in,
                              void* d_out, int out_size, void* d_ws, size_t ws_size,
                              hipStream_t stream)
{
  const float* yin = (const float*)d_in[0];   // (5, 1024, 2048) f32
  const float* vin = (const float*)d_in[1];   // (2, 1024, 2048) f32
  float* out = (float*)d_out;                 // (5, 1024, 2048) f32

  // ws layout: [PAD_ floats][gY: 7ch][B: 5ch]  (B doubles as over-read pad
  // after gY; the PAD_ floats absorb the 4-float under-read before gY)
  float* gY = (float*)d_ws + PAD_;
  float* B  = gY + 7 * (size_t)YX_;

  // Host-computed Gaussian taps (double->float, matches numpy to ~1 ulp) and
  // the derivative-of-smooth 27-tap kernel Dx[t] = 0.5*(K[t-2]-K[t]).
  W25 W; D27 D;
  double wd[NT_], s = 0.0;
  for (int i = 0; i < NT_; ++i) {
    const double x = i - RAD_;
    wd[i] = exp(-0.5 * (x / 3.0) * (x / 3.0));
    s += wd[i];
  }
  for (int i = 0; i < NT_; ++i) W.w[i] = (float)(wd[i] / s);
  for (int t = 0; t < ND_; ++t) {
    const double a = (t - 2 >= 0 && t - 2 < NT_) ? wd[t - 2] / s : 0.0;
    const double b = (t < NT_) ? wd[t] / s : 0.0;
    D.d[t] = (float)(0.5 * (a - b));
  }

  ksmooth_y7<<<dim3(2,  64, 7), 256, 0, stream>>>(yin, vin, gY, W);
  kgradpoint<<<dim3(2, 1024, 1), 256, 0, stream>>>(gY, yin, vin, B, W, D);
  kpost     <<<dim3(2,  64, 5), 256, 0, stream>>>(B, out, W);
}